// Round 4
// baseline (753.833 us; speedup 1.0000x reference)
//
#include <hip/hip_runtime.h>
#include <hip/hip_bf16.h>

// Problem constants (fixed by the reference)
#define VOCAB 50000
#define D     300
#define B_    64
#define LC    32
#define T_    256
#define LT    64
#define NSEL  5

#define CROWF4 80             // padded float4 slots per claim row (XOR-swizzle space)
#define CIMG4  (LC * CROWF4)  // 2560 float4 per batch claim image
#define CIMG   (CIMG4 * 4)    // 10240 floats
#define K4N    75             // 300/4 float4 per row
#define NCH    5              // k-chunks per tile
#define CHK4   15             // float4 per row per chunk (5*15 = 75)
#define TT     4              // tiles (t's) per block in k_scores

// ws layout (floats):
//   wsC   : [B_][CIMG]  claim images, row c at c*320 floats; float4 slot for
//                        k4 stored at (k4 ^ cg) where cg = (c>>2)&7.
//                        Compute read bank: 4*((k4^cg)&7) -> 8 distinct quads
//                        across cg (320 % 32 == 0) -> conflict-free broadcast.
//   wsScr : [B_][T_]    target scores
//   wsIdx : [B_][NSEL]  top-5 indices (ints)

__device__ __forceinline__ float dot4acc(float4 c, float4 e, float a) {
    a = fmaf(c.x, e.x, a); a = fmaf(c.y, e.y, a);
    a = fmaf(c.z, e.z, a); a = fmaf(c.w, e.w, a);
    return a;
}

// ---------------- K1: gather claim embeddings into swizzled image ------------
__global__ void k_gather_claim(const int* __restrict__ claim,
                               const float* __restrict__ emb,
                               float* __restrict__ wsC) {
    int row = blockIdx.x;            // 0..B_*LC-1
    int b = row >> 5, c = row & 31;
    int key = (c >> 2) & 7;
    int tok = claim[row];
    const float* src = emb + (size_t)tok * D;
    float* dst = wsC + (size_t)b * CIMG + c * (CROWF4 * 4);
    for (int k = threadIdx.x; k < D; k += 64) {
        dst[(((k >> 2) ^ key) << 2) + (k & 3)] = src[k];
    }
}

// ---- staging helpers: 256 threads stage one chunk (64 rows x 15 float4) ----
// srow = tid>>2 (row 0..63), sq = tid&3; quad reads 64B contiguous per step.
__device__ __forceinline__ void prefetch_chunk(const int* __restrict__ tbase,
                                               const float* __restrict__ emb,
                                               int t, int chunk, int srow, int sq,
                                               float4 pf[4]) {
    int tok = tbase[t * LT + srow];
    const float4* ep = (const float4*)(emb + (size_t)tok * D) + chunk * CHK4;
#pragma unroll
    for (int s2 = 0; s2 < 4; ++s2) {
        int k4i = s2 * 4 + sq;
        if (k4i < CHK4) pf[s2] = ep[k4i];
    }
}
__device__ __forceinline__ void write_chunk(float4* __restrict__ buf,
                                            int srow, int sq, const float4 pf[4]) {
#pragma unroll
    for (int s2 = 0; s2 < 4; ++s2) {
        int k4i = s2 * 4 + sq;
        if (k4i < CHK4) buf[srow * CHK4 + k4i] = pf[s2];
    }
}

// ---- per-chunk compute: lane (cg=lane>>3, lg=lane&7) of wave w owns
// c in {cg*4..+4}, l in {w*16 + lg*2 + {0,1}}. 6 ds_read_b128 per 32 FMAs. ----
__device__ __forceinline__ void compute_chunk(const float4* __restrict__ sC4,
                                              const float4* __restrict__ tb,
                                              int k4b, int cg, int lg, int w,
                                              float acc[4][2]) {
#pragma unroll 3
    for (int k4i = 0; k4i < CHK4; ++k4i) {
        float4 tv0 = tb[(w * 16 + lg * 2 + 0) * CHK4 + k4i];
        float4 tv1 = tb[(w * 16 + lg * 2 + 1) * CHK4 + k4i];
#pragma unroll
        for (int i = 0; i < 4; ++i) {
            float4 cv = sC4[(cg * 4 + i) * CROWF4 + ((k4b + k4i) ^ cg)];
            acc[i][0] = dot4acc(cv, tv0, acc[i][0]);
            acc[i][1] = dot4acc(cv, tv1, acc[i][1]);
        }
    }
}

// ---------------- K2: target scores ------------------------------------------
__global__ __launch_bounds__(256, 2) void k_scores(const int* __restrict__ targets,
                                                   const float* __restrict__ emb,
                                                   const float* __restrict__ wsC,
                                                   float* __restrict__ wsScr) {
    __shared__ __align__(16) float4 sC4[CIMG4];          // 40960 B
    __shared__ __align__(16) float4 sT[2][LT * CHK4];    // 2 x 15360 B
    __shared__ float sM[LC * 4], sS[LC * 4], sW[4];
    int b = blockIdx.y, tid = threadIdx.x;
    {
        const float4* csrc = (const float4*)(wsC + (size_t)b * CIMG);
        for (int i = tid; i < CIMG4; i += 256) sC4[i] = csrc[i];
    }
    int w = tid >> 6, lane = tid & 63, cg = lane >> 3, lg = lane & 7;
    int srow = tid >> 2, sq = tid & 3;
    const int* tbase = targets + (size_t)b * T_ * LT;
    int t0 = blockIdx.x * TT;

    float4 pf[4];
    prefetch_chunk(tbase, emb, t0, 0, srow, sq, pf);
    __syncthreads();                          // claim image visible
    write_chunk(sT[0], srow, sq, pf);
    __syncthreads();                          // chunk 0 visible

    float acc[4][2];
    for (int stage = 0; stage < TT * NCH; ++stage) {
        int tile = stage / NCH, chunk = stage - tile * NCH;
        if (stage + 1 < TT * NCH) {
            int s1 = stage + 1, tl = s1 / NCH, ch = s1 - tl * NCH;
            prefetch_chunk(tbase, emb, t0 + tl, ch, srow, sq, pf);
        }
        if (chunk == 0) {
#pragma unroll
            for (int i = 0; i < 4; ++i) { acc[i][0] = 0.f; acc[i][1] = 0.f; }
        }
        compute_chunk(sC4, sT[stage & 1], chunk * CHK4, cg, lg, w, acc);

        if (chunk == NCH - 1) {               // ---- epilogue for this tile ----
            int t = t0 + tile;
            float m[4];
#pragma unroll
            for (int i = 0; i < 4; ++i) {     // A: per-c max over l
                float v = fmaxf(acc[i][0], acc[i][1]);
                v = fmaxf(v, __shfl_xor(v, 1));
                v = fmaxf(v, __shfl_xor(v, 2));
                v = fmaxf(v, __shfl_xor(v, 4));
                m[i] = v;
            }
            if (lg == 0) {
#pragma unroll
                for (int i = 0; i < 4; ++i) sM[(cg * 4 + i) * 4 + w] = m[i];
            }
            __syncthreads();
#pragma unroll
            for (int i = 0; i < 4; ++i) {
                const float* r = sM + (cg * 4 + i) * 4;
                m[i] = fmaxf(fmaxf(r[0], r[1]), fmaxf(r[2], r[3]));
            }
            float p[4][2], s[4];
#pragma unroll
            for (int i = 0; i < 4; ++i) {     // B: exp + denom
                p[i][0] = __expf(acc[i][0] - m[i]);
                p[i][1] = __expf(acc[i][1] - m[i]);
                float v = p[i][0] + p[i][1];
                v += __shfl_xor(v, 1);
                v += __shfl_xor(v, 2);
                v += __shfl_xor(v, 4);
                s[i] = v;
            }
            if (lg == 0) {
#pragma unroll
                for (int i = 0; i < 4; ++i) sS[(cg * 4 + i) * 4 + w] = s[i];
            }
            __syncthreads();
#pragma unroll
            for (int i = 0; i < 4; ++i) {
                const float* r = sS + (cg * 4 + i) * 4;
                float rv = 1.0f / (r[0] + r[1] + r[2] + r[3]);
                p[i][0] *= rv; p[i][1] *= rv;
            }
            // C: per-l max over c (in-wave: all 32 c live in every wave)
            float q0 = fmaxf(fmaxf(p[0][0], p[1][0]), fmaxf(p[2][0], p[3][0]));
            float q1 = fmaxf(fmaxf(p[0][1], p[1][1]), fmaxf(p[2][1], p[3][1]));
            q0 = fmaxf(q0, __shfl_xor(q0, 8));
            q0 = fmaxf(q0, __shfl_xor(q0, 16));
            q0 = fmaxf(q0, __shfl_xor(q0, 32));
            q1 = fmaxf(q1, __shfl_xor(q1, 8));
            q1 = fmaxf(q1, __shfl_xor(q1, 16));
            q1 = fmaxf(q1, __shfl_xor(q1, 32));
            float ts = q0 + q1;               // this wave's 16 l's
            ts += __shfl_xor(ts, 1);
            ts += __shfl_xor(ts, 2);
            ts += __shfl_xor(ts, 4);
            if (lane == 0) sW[w] = ts;
            __syncthreads();
            if (tid == 0) wsScr[b * T_ + t] = sW[0] + sW[1] + sW[2] + sW[3];
        }
        if (stage + 1 < TT * NCH) write_chunk(sT[(stage + 1) & 1], srow, sq, pf);
        __syncthreads();
    }
}

// ---------------- K3: top-5 per batch (descending, lowest-index ties) --------
__global__ void k_topn(const float* __restrict__ wsScr, int* __restrict__ wsIdx) {
    int b = blockIdx.x;
    int tid = threadIdx.x;              // 64 threads = 1 wave
    float v[4];
    for (int i = 0; i < 4; ++i) v[i] = wsScr[b * T_ + tid + 64 * i];
    for (int r = 0; r < NSEL; ++r) {
        float bv = v[0]; int bi = tid;
        for (int i = 1; i < 4; ++i) {
            int idx = tid + 64 * i;
            if (v[i] > bv) { bv = v[i]; bi = idx; }
        }
        for (int off = 32; off > 0; off >>= 1) {
            float ov = __shfl_down(bv, off);
            int   oi = __shfl_down(bi, off);
            if (ov > bv || (ov == bv && oi < bi)) { bv = ov; bi = oi; }
        }
        bi = __shfl(bi, 0);
        if (tid == 0) wsIdx[b * NSEL + r] = bi;
        if ((bi & 63) == tid) v[bi >> 6] = -1e30f;   // remove winner
    }
}

// ---------------- K4: recompute selected tiles, L2-normalize rows ------------
__global__ __launch_bounds__(256, 2) void k_output(const int* __restrict__ targets,
                                                   const float* __restrict__ emb,
                                                   const float* __restrict__ wsC,
                                                   const int* __restrict__ wsIdx,
                                                   float* __restrict__ out) {
    __shared__ __align__(16) float4 sC4[CIMG4];
    __shared__ __align__(16) float4 sT[2][LT * CHK4];
    __shared__ float sS[LC * 4];
    int b = blockIdx.y, j = blockIdx.x, tid = threadIdx.x;
    {
        const float4* csrc = (const float4*)(wsC + (size_t)b * CIMG);
        for (int i = tid; i < CIMG4; i += 256) sC4[i] = csrc[i];
    }
    int w = tid >> 6, lane = tid & 63, cg = lane >> 3, lg = lane & 7;
    int srow = tid >> 2, sq = tid & 3;
    const int* tbase = targets + (size_t)b * T_ * LT;
    int t = wsIdx[b * NSEL + j];

    float4 pf[4];
    prefetch_chunk(tbase, emb, t, 0, srow, sq, pf);
    __syncthreads();
    write_chunk(sT[0], srow, sq, pf);
    __syncthreads();

    float acc[4][2];
#pragma unroll
    for (int i = 0; i < 4; ++i) { acc[i][0] = 0.f; acc[i][1] = 0.f; }
    for (int chunk = 0; chunk < NCH; ++chunk) {
        if (chunk + 1 < NCH) prefetch_chunk(tbase, emb, t, chunk + 1, srow, sq, pf);
        compute_chunk(sC4, sT[chunk & 1], chunk * CHK4, cg, lg, w, acc);
        if (chunk + 1 < NCH) write_chunk(sT[(chunk + 1) & 1], srow, sq, pf);
        __syncthreads();
    }

    float s[4];
#pragma unroll
    for (int i = 0; i < 4; ++i) {       // sum of squares over l
        float v = acc[i][0] * acc[i][0] + acc[i][1] * acc[i][1];
        v += __shfl_xor(v, 1);
        v += __shfl_xor(v, 2);
        v += __shfl_xor(v, 4);
        s[i] = v;
    }
    if (lg == 0) {
#pragma unroll
        for (int i = 0; i < 4; ++i) sS[(cg * 4 + i) * 4 + w] = s[i];
    }
    __syncthreads();
    float* orow = out + (size_t)(b * NSEL + j) * (LC * LT);
#pragma unroll
    for (int i = 0; i < 4; ++i) {
        const float* r = sS + (cg * 4 + i) * 4;
        float rinv = 1.0f / sqrtf(r[0] + r[1] + r[2] + r[3]);
        int l = w * 16 + lg * 2;
        orow[(cg * 4 + i) * LT + l + 0] = acc[i][0] * rinv;
        orow[(cg * 4 + i) * LT + l + 1] = acc[i][1] * rinv;
    }
}

extern "C" void kernel_launch(void* const* d_in, const int* in_sizes, int n_in,
                              void* d_out, int out_size, void* d_ws, size_t ws_size,
                              hipStream_t stream) {
    const int*   claim   = (const int*)d_in[0];
    const int*   targets = (const int*)d_in[1];
    const float* emb     = (const float*)d_in[2];
    // d_in[3] is n (=5), compile-time NSEL

    float* wsC   = (float*)d_ws;
    float* wsScr = wsC + (size_t)B_ * CIMG;
    int*   wsIdx = (int*)(wsScr + B_ * T_);
    float* out   = (float*)d_out;

    k_gather_claim<<<dim3(B_ * LC), dim3(64), 0, stream>>>(claim, emb, wsC);
    k_scores<<<dim3(T_ / TT, B_), dim3(256), 0, stream>>>(targets, emb, wsC, wsScr);
    k_topn<<<dim3(B_), dim3(64), 0, stream>>>(wsScr, wsIdx);
    k_output<<<dim3(NSEL, B_), dim3(256), 0, stream>>>(targets, emb, wsC, wsIdx, out);
}

// Round 6
// 321.055 us; speedup vs baseline: 2.3480x; 2.3480x over previous
//
#include <hip/hip_runtime.h>
#include <hip/hip_bf16.h>

// Problem constants (fixed by the reference)
#define VOCAB 50000
#define D     300
#define B_    64
#define LC    32
#define T_    256
#define LT    64
#define NSEL  5

// A-image geometry: 32 rows x 40 slots (16B = 8 f16 each), k padded 300->320,
// slot for k-block s stored at s ^ (m&7)  -> conflict-free ds_read_b128.
// hi region: uint4[0..1280), lo region: uint4[1280..2560). 40960 B per batch.
#define A_U4   2560
#define A_HALF 20480

typedef _Float16 half8_t __attribute__((ext_vector_type(8)));
typedef float    f32x4   __attribute__((ext_vector_type(4)));

// ws layout:
//   wsA   : [B_][40960 B]  f16 hi/lo claim images (swizzled)
//   wsScr : [B_][T_] float
//   wsIdx : [B_][NSEL] int

// ---------------- K1: claim -> f16 hi/lo swizzled image in ws ----------------
__global__ void k_prep_claim(const int* __restrict__ claim,
                             const float* __restrict__ emb,
                             _Float16* __restrict__ wsA) {
    int row = blockIdx.x;                 // 0..B_*LC-1
    int b = row >> 5, m = row & 31;
    int tok = claim[row];
    const float* src = emb + (size_t)tok * D;
    _Float16* base = wsA + (size_t)b * A_HALF;
    for (int k = threadIdx.x; k < 320; k += 64) {
        float x = (k < D) ? src[k] : 0.0f;
        _Float16 h = (_Float16)x;
        float r = x - (float)h;
        _Float16 l = (_Float16)r;
        int sp = ((k >> 3) ^ (m & 7));
        int idx = (m * 40 + sp) * 8 + (k & 7);
        base[idx] = h;
        base[10240 + idx] = l;
    }
}

// hi/lo split of a float4 pair into half8 hi and half8 lo
__device__ __forceinline__ void split8(const float4& a, const float4& b,
                                       half8_t& hv, half8_t& lv) {
    float x[8] = {a.x, a.y, a.z, a.w, b.x, b.y, b.z, b.w};
#pragma unroll
    for (int i = 0; i < 8; ++i) {
        _Float16 h = (_Float16)x[i];
        hv[i] = h;
        lv[i] = (_Float16)(x[i] - (float)h);
    }
}

// ---------------- shared K-loop: U tile via f16x2-split MFMA ------------------
// Wave owns one t. acc[mi][ni] = 16x16 tile (c = mi*16+quad*4+reg, l = ni*16+ln).
__device__ __forceinline__ void compute_U(const uint4* sA,
                                          const float* __restrict__ emb,
                                          const int* __restrict__ trow,
                                          int lane, f32x4 acc[2][4]) {
    int ln = lane & 15, quad = lane >> 4;
    const float* bp[4];
#pragma unroll
    for (int ni = 0; ni < 4; ++ni) {
        int tok = trow[ni * 16 + ln];
        bp[ni] = emb + (size_t)tok * D;
    }
#pragma unroll
    for (int mi = 0; mi < 2; ++mi)
#pragma unroll
        for (int ni = 0; ni < 4; ++ni) acc[mi][ni] = (f32x4)0.0f;

    int arow0 = ln * 40;            // m = ln      (mi=0)
    int arow1 = (16 + ln) * 40;     // m = 16+ln   (mi=1)
    int key = ln & 7;

#pragma unroll 1
    for (int ks = 0; ks < 10; ++ks) {
        int kb = ks * 32 + quad * 8;          // logical k base for this lane
        int ka = kb > 296 ? 296 : kb;         // clamped, always in-row
        int kb4 = kb + 4;
        int kbb = kb4 > 296 ? 296 : kb4;
        float4 b0[4], b1[4];
#pragma unroll
        for (int ni = 0; ni < 4; ++ni) {
            b0[ni] = *(const float4*)(bp[ni] + ka);
            b1[ni] = *(const float4*)(bp[ni] + kbb);
        }
        if (kb >= 296) {                      // tail (ks==9, quad>=1)
            float4 z = make_float4(0.f, 0.f, 0.f, 0.f);
#pragma unroll
            for (int ni = 0; ni < 4; ++ni) {
                if (kb >= 300) b0[ni] = z;    // quads 2,3: fully past K
                b1[ni] = z;                   // kb+4 >= 300 always here
            }
        }

        int sp = (ks * 4 + quad) ^ key;
        half8_t ah[2], al[2];
        ah[0] = __builtin_bit_cast(half8_t, sA[arow0 + sp]);
        al[0] = __builtin_bit_cast(half8_t, sA[1280 + arow0 + sp]);
        ah[1] = __builtin_bit_cast(half8_t, sA[arow1 + sp]);
        al[1] = __builtin_bit_cast(half8_t, sA[1280 + arow1 + sp]);

        half8_t bh[4], bl[4];
#pragma unroll
        for (int ni = 0; ni < 4; ++ni) split8(b0[ni], b1[ni], bh[ni], bl[ni]);

#pragma unroll
        for (int mi = 0; mi < 2; ++mi)
#pragma unroll
            for (int ni = 0; ni < 4; ++ni) {
                acc[mi][ni] = __builtin_amdgcn_mfma_f32_16x16x32_f16(ah[mi], bh[ni], acc[mi][ni], 0, 0, 0);
                acc[mi][ni] = __builtin_amdgcn_mfma_f32_16x16x32_f16(ah[mi], bl[ni], acc[mi][ni], 0, 0, 0);
                acc[mi][ni] = __builtin_amdgcn_mfma_f32_16x16x32_f16(al[mi], bh[ni], acc[mi][ni], 0, 0, 0);
            }
    }
}

__device__ __forceinline__ float xmax4(float v) {
    v = fmaxf(v, __shfl_xor(v, 1)); v = fmaxf(v, __shfl_xor(v, 2));
    v = fmaxf(v, __shfl_xor(v, 4)); v = fmaxf(v, __shfl_xor(v, 8));
    return v;
}
__device__ __forceinline__ float xsum4(float v) {
    v += __shfl_xor(v, 1); v += __shfl_xor(v, 2);
    v += __shfl_xor(v, 4); v += __shfl_xor(v, 8);
    return v;
}

// ---------------- K2: target scores (wave-per-t, barrier-free K-loop) --------
__global__ __launch_bounds__(256, 3) void k_scores(const int* __restrict__ targets,
                                                   const float* __restrict__ emb,
                                                   const _Float16* __restrict__ wsA,
                                                   float* __restrict__ wsScr) {
    __shared__ __align__(16) uint4 sA[A_U4];   // 40960 B -> 3 blocks/CU
    int b = blockIdx.y, tid = threadIdx.x;
    {
        const uint4* src = (const uint4*)(wsA + (size_t)b * A_HALF);
        for (int i = tid; i < A_U4; i += 256) sA[i] = src[i];
    }
    __syncthreads();

    int lane = tid & 63, wave = tid >> 6;
    int t = blockIdx.x * 4 + wave;
    const int* trow = targets + ((size_t)b * T_ + t) * LT;

    f32x4 acc[2][4];
    compute_U(sA, emb, trow, lane, acc);

    // softmax over l per c, max over c, sum over l — all in-wave
    float score_l[4] = {0.f, 0.f, 0.f, 0.f};
#pragma unroll
    for (int mi = 0; mi < 2; ++mi)
#pragma unroll
        for (int r = 0; r < 4; ++r) {
            float m = fmaxf(fmaxf(acc[mi][0][r], acc[mi][1][r]),
                            fmaxf(acc[mi][2][r], acc[mi][3][r]));
            m = xmax4(m);                     // max over 64 l for this c
            float p[4], s = 0.f;
#pragma unroll
            for (int ni = 0; ni < 4; ++ni) { p[ni] = __expf(acc[mi][ni][r] - m); s += p[ni]; }
            s = xsum4(s);                     // denom over 64 l
            float rv = 1.0f / s;
#pragma unroll
            for (int ni = 0; ni < 4; ++ni) score_l[ni] = fmaxf(score_l[ni], p[ni] * rv);
        }
    float tot = 0.f;
#pragma unroll
    for (int ni = 0; ni < 4; ++ni) {
        float v = score_l[ni];                // fold max over c across quads
        v = fmaxf(v, __shfl_xor(v, 16));
        v = fmaxf(v, __shfl_xor(v, 32));
        tot += v;
    }
    tot = xsum4(tot);                         // sum over the 16 ln-columns
    if (lane == 0) wsScr[b * T_ + t] = tot;
}

// ---------------- K3: top-5 per batch (descending, lowest-index ties) --------
__global__ void k_topn(const float* __restrict__ wsScr, int* __restrict__ wsIdx) {
    int b = blockIdx.x;
    int tid = threadIdx.x;              // 64 threads = 1 wave
    float v[4];
    for (int i = 0; i < 4; ++i) v[i] = wsScr[b * T_ + tid + 64 * i];
    for (int r = 0; r < NSEL; ++r) {
        float bv = v[0]; int bi = tid;
        for (int i = 1; i < 4; ++i) {
            int idx = tid + 64 * i;
            if (v[i] > bv) { bv = v[i]; bi = idx; }
        }
        for (int off = 32; off > 0; off >>= 1) {
            float ov = __shfl_down(bv, off);
            int   oi = __shfl_down(bi, off);
            if (ov > bv || (ov == bv && oi < bi)) { bv = ov; bi = oi; }
        }
        bi = __shfl(bi, 0);
        if (tid == 0) wsIdx[b * NSEL + r] = bi;
        if ((bi & 63) == tid) v[bi >> 6] = -1e30f;   // remove winner
    }
}

// ---------------- K4: recompute selected tiles, L2-normalize rows ------------
__global__ __launch_bounds__(64) void k_output(const int* __restrict__ targets,
                                               const float* __restrict__ emb,
                                               const _Float16* __restrict__ wsA,
                                               const int* __restrict__ wsIdx,
                                               float* __restrict__ out) {
    __shared__ __align__(16) uint4 sA[A_U4];
    int b = blockIdx.y, j = blockIdx.x;
    int lane = threadIdx.x;             // 1 wave = 1 tile
    {
        const uint4* src = (const uint4*)(wsA + (size_t)b * A_HALF);
        for (int i = lane; i < A_U4; i += 64) sA[i] = src[i];
    }
    __syncthreads();

    int t = wsIdx[b * NSEL + j];
    const int* trow = targets + ((size_t)b * T_ + t) * LT;
    f32x4 acc[2][4];
    compute_U(sA, emb, trow, lane, acc);

    int ln = lane & 15, quad = lane >> 4;
    float* obase = out + (size_t)(b * NSEL + j) * (LC * LT);
#pragma unroll
    for (int mi = 0; mi < 2; ++mi)
#pragma unroll
        for (int r = 0; r < 4; ++r) {
            float ss = 0.f;
#pragma unroll
            for (int ni = 0; ni < 4; ++ni) ss = fmaf(acc[mi][ni][r], acc[mi][ni][r], ss);
            ss = xsum4(ss);                          // sum over 64 l
            float rinv = 1.0f / sqrtf(ss);
            int c = mi * 16 + quad * 4 + r;
#pragma unroll
            for (int ni = 0; ni < 4; ++ni)
                obase[c * LT + ni * 16 + ln] = acc[mi][ni][r] * rinv;
        }
}

extern "C" void kernel_launch(void* const* d_in, const int* in_sizes, int n_in,
                              void* d_out, int out_size, void* d_ws, size_t ws_size,
                              hipStream_t stream) {
    const int*   claim   = (const int*)d_in[0];
    const int*   targets = (const int*)d_in[1];
    const float* emb     = (const float*)d_in[2];
    // d_in[3] is n (=5), compile-time NSEL

    _Float16* wsA = (_Float16*)d_ws;
    float* wsScr  = (float*)((char*)d_ws + (size_t)B_ * A_HALF * sizeof(_Float16));
    int*   wsIdx  = (int*)(wsScr + B_ * T_);
    float* out    = (float*)d_out;

    k_prep_claim<<<dim3(B_ * LC), dim3(64), 0, stream>>>(claim, emb, wsA);
    k_scores<<<dim3(T_ / 4, B_), dim3(256), 0, stream>>>(targets, emb, wsA, wsScr);
    k_topn<<<dim3(B_), dim3(64), 0, stream>>>(wsScr, wsIdx);
    k_output<<<dim3(NSEL, B_), dim3(64), 0, stream>>>(targets, emb, wsA, wsIdx, out);
}